// Round 3
// baseline (166.675 us; speedup 1.0000x reference)
//
#include <hip/hip_runtime.h>

// BoxConv2d: out[b, c*F+f, h, w] = bilinear box-sum via integral image.
// One block per (b,c, half-of-F). Integral image in LDS (129 rows x 132 stride).
// Per (f,h): wave builds Drow[0..128] (row interpolation) in wave-private LDS,
// then column-interpolates 128 outputs.

__global__ __launch_bounds__(256, 2)
void boxconv_kernel(const float* __restrict__ in,
                    const float* __restrict__ x_min,
                    const float* __restrict__ x_max,
                    const float* __restrict__ y_min,
                    const float* __restrict__ y_max,
                    float* __restrict__ out)
{
    constexpr int H = 128, W = 128, C = 32, F = 8;
    constexpr int STRIDE = 132;   // I row stride (floats); mult of 4 -> 16B-aligned rows
    constexpr int NROW = 129;

    __shared__ float I[NROW * STRIDE];    // 68112 B
    __shared__ float Dbuf[4][STRIDE];     // wave-private Drow buffers, 2112 B

    const int tid  = threadIdx.x;
    const int lane = tid & 63;
    const int wid  = tid >> 6;

    const int bc   = blockIdx.x >> 1;     // 0..255 -> (b,c)
    const int half = blockIdx.x & 1;      // which 4 filters
    const int b    = bc >> 5;
    const int c    = bc & 31;

    // ---- zero I (row 0, col 0, pad cols must be 0; rest overwritten) ----
    {
        float4 z = make_float4(0.f, 0.f, 0.f, 0.f);
        float4* I4 = (float4*)I;
        for (int idx = tid; idx < (NROW * STRIDE) / 4; idx += 256) I4[idx] = z;
    }
    __syncthreads();

    // ---- row scans: thread r scans input row r (float4 loads), write I[r+1][1..128] ----
    const float* img = in + (size_t)bc * (H * W);
    if (tid < H) {
        const int r = tid;
        const float4* row4 = (const float4*)(img + r * W);
        float* Irow = I + (r + 1) * STRIDE + 1;
        float acc = 0.f;
        #pragma unroll 8
        for (int w4 = 0; w4 < W / 4; ++w4) {
            float4 v = row4[w4];
            float s0 = acc + v.x;
            float s1 = s0 + v.y;
            float s2 = s1 + v.z;
            float s3 = s2 + v.w;
            Irow[w4 * 4 + 0] = s0;
            Irow[w4 * 4 + 1] = s1;
            Irow[w4 * 4 + 2] = s2;
            Irow[w4 * 4 + 3] = s3;
            acc = s3;
        }
    }
    __syncthreads();

    // ---- col scans: thread t scans column t+1 over rows 1..128, reg-chunked ----
    if (tid < W) {
        const int cc = tid + 1;
        float acc = 0.f;
        for (int chunk = 0; chunk < 4; ++chunk) {
            const int r0 = 1 + chunk * 32;
            float v[32];
            #pragma unroll
            for (int i = 0; i < 32; ++i) v[i] = I[(r0 + i) * STRIDE + cc];
            #pragma unroll
            for (int i = 0; i < 32; ++i) { acc += v[i]; v[i] = acc; }
            #pragma unroll
            for (int i = 0; i < 32; ++i) I[(r0 + i) * STRIDE + cc] = v[i];
        }
    }
    __syncthreads();

    float* outbc = out + ((size_t)b * (C * F) + (size_t)c * F) * (H * W);

    for (int fi = 0; fi < 4; ++fi) {
        const int f = half * 4 + fi;
        const float xm = x_min[c * F + f] * 128.f;
        const float xM = x_max[c * F + f] * 128.f;
        const float ym = y_min[c * F + f] * 128.f;
        const float yM = y_max[c * F + f] * 128.f;

        // column coefficients for w = lane, lane+64 (hoisted out of h loop)
        int   j0[2], j1[2];
        float b0v[2], b1v[2], cb0[2], cb1[2];
        #pragma unroll
        for (int k = 0; k < 2; ++k) {
            const float wf = (float)(lane + 64 * k);
            const float v0 = fminf(fmaxf(wf + ym, 0.f), 128.f);
            const float v1 = fminf(fmaxf(wf + yM + 1.f, 0.f), 128.f);
            const float j0f = fminf(floorf(v0), 127.f);
            const float j1f = fminf(floorf(v1), 127.f);
            j0[k] = (int)j0f;  j1[k] = (int)j1f;
            b0v[k] = v0 - j0f; b1v[k] = v1 - j1f;
            cb0[k] = 1.f - b0v[k]; cb1[k] = 1.f - b1v[k];
        }

        float* Dw = Dbuf[wid];
        float* outf = outbc + (size_t)f * (H * W);

        for (int h = wid; h < H; h += 4) {
            const float hf = (float)h;
            const float u0 = fminf(fmaxf(hf + xm, 0.f), 128.f);
            const float u1 = fminf(fmaxf(hf + xM + 1.f, 0.f), 128.f);
            const float i0f = fminf(floorf(u0), 127.f);
            const float i1f = fminf(floorf(u1), 127.f);
            const int   i0  = (int)i0f, i1 = (int)i1f;
            const float a0 = u0 - i0f, a1 = u1 - i1f;
            const float ca0 = 1.f - a0, ca1 = 1.f - a1;

            // Stage A: Drow[wp] = ca1*I[i1][wp] + a1*I[i1+1][wp] - ca0*I[i0][wp] - a0*I[i0+1][wp]
            // lanes 0..32 each cover 4 consecutive wp via b128 (wp 128..131: pad, never read back except 128)
            if (lane < 33) {
                const int wp = lane * 4;
                const float4 q0  = *(const float4*)(I + i0 * STRIDE + wp);
                const float4 q0b = *(const float4*)(I + (i0 + 1) * STRIDE + wp);
                const float4 q1  = *(const float4*)(I + i1 * STRIDE + wp);
                const float4 q1b = *(const float4*)(I + (i1 + 1) * STRIDE + wp);
                float4 d;
                d.x = ca1 * q1.x + a1 * q1b.x - ca0 * q0.x - a0 * q0b.x;
                d.y = ca1 * q1.y + a1 * q1b.y - ca0 * q0.y - a0 * q0b.y;
                d.z = ca1 * q1.z + a1 * q1b.z - ca0 * q0.z - a0 * q0b.z;
                d.w = ca1 * q1.w + a1 * q1b.w - ca0 * q0.w - a0 * q0b.w;
                *(float4*)(Dw + wp) = d;
            }
            // wave-synchronous: same wave wrote Dw, compiler inserts lgkmcnt wait

            // Stage B: column interpolation, 2 outputs per lane
            #pragma unroll
            for (int k = 0; k < 2; ++k) {
                const float Dj0  = Dw[j0[k]];
                const float Dj0p = Dw[j0[k] + 1];
                const float Dj1  = Dw[j1[k]];
                const float Dj1p = Dw[j1[k] + 1];
                outf[h * W + lane + 64 * k] =
                    cb1[k] * Dj1 + b1v[k] * Dj1p - cb0[k] * Dj0 - b0v[k] * Dj0p;
            }
        }
    }
}

extern "C" void kernel_launch(void* const* d_in, const int* in_sizes, int n_in,
                              void* d_out, int out_size, void* d_ws, size_t ws_size,
                              hipStream_t stream) {
    const float* in    = (const float*)d_in[0];
    const float* x_min = (const float*)d_in[1];
    const float* x_max = (const float*)d_in[2];
    const float* y_min = (const float*)d_in[3];
    const float* y_max = (const float*)d_in[4];
    float* outp = (float*)d_out;

    boxconv_kernel<<<dim3(8 * 32 * 2), dim3(256), 0, stream>>>(
        in, x_min, x_max, y_min, y_max, outp);
}

// Round 4
// 157.473 us; speedup vs baseline: 1.0584x; 1.0584x over previous
//
#include <hip/hip_runtime.h>

// BoxConv2d via LDS integral image.
// One block per (b,c), 1024 threads = 16 waves. Wave = (filter f = wid>>1, h-half).
// Per iteration: 2 h-rows. Stage A: all 64 lanes (lanes 0-31 row h, 32-63 row h+1)
// build Drow (row-interp diff of integral rows) into wave-private LDS.
// Stage B: stride-1 gathers column-interpolate 2 cols x 2 rows per lane.

__global__ __launch_bounds__(1024, 4)
void boxconv_kernel(const float* __restrict__ in,
                    const float* __restrict__ x_min,
                    const float* __restrict__ x_max,
                    const float* __restrict__ y_min,
                    const float* __restrict__ y_max,
                    float* __restrict__ out)
{
    constexpr int H = 128, W = 128, C = 32, F = 8;
    constexpr int STRIDE = 132;   // I row stride (floats); 16B-aligned rows
    constexpr int NROW = 129;

    __shared__ float I[NROW * STRIDE];        // 68112 B
    __shared__ float Dbuf[16][2 * STRIDE];    // per-wave 2-row Drow, 16896 B

    const int tid  = threadIdx.x;
    const int lane = tid & 63;
    const int wid  = tid >> 6;
    const int bc   = blockIdx.x;      // b*32 + c
    const int c    = bc & 31;

    // ---- minimal zero: col 0 (rows 0..128) and row 0 (cols 1..131); rest overwritten ----
    if (tid < NROW)                    I[tid * STRIDE] = 0.f;
    else if (tid >= 256 && tid < 256 + STRIDE - 1) I[tid - 255] = 0.f;  // row0 cols 1..131
    __syncthreads();

    // ---- row scans: thread r scans input row r (float4 loads), writes I[r+1][1..128] ----
    const float* img = in + (size_t)bc * (H * W);
    if (tid < H) {
        const int r = tid;
        const float4* row4 = (const float4*)(img + r * W);
        float* Irow = I + (r + 1) * STRIDE + 1;
        float acc = 0.f;
        #pragma unroll 8
        for (int w4 = 0; w4 < W / 4; ++w4) {
            float4 v = row4[w4];
            float s0 = acc + v.x;
            float s1 = s0 + v.y;
            float s2 = s1 + v.z;
            float s3 = s2 + v.w;
            Irow[w4 * 4 + 0] = s0;
            Irow[w4 * 4 + 1] = s1;
            Irow[w4 * 4 + 2] = s2;
            Irow[w4 * 4 + 3] = s3;
            acc = s3;
        }
    }
    __syncthreads();

    // ---- col scans: thread t scans column t+1 over rows 1..128, reg-chunked ----
    if (tid < W) {
        const int cc = tid + 1;
        float acc = 0.f;
        for (int chunk = 0; chunk < 4; ++chunk) {
            const int r0 = 1 + chunk * 32;
            float v[32];
            #pragma unroll
            for (int i = 0; i < 32; ++i) v[i] = I[(r0 + i) * STRIDE + cc];
            #pragma unroll
            for (int i = 0; i < 32; ++i) { acc += v[i]; v[i] = acc; }
            #pragma unroll
            for (int i = 0; i < 32; ++i) I[(r0 + i) * STRIDE + cc] = v[i];
        }
    }
    __syncthreads();

    // ---- main loop: wave = (f, h-half) ----
    const int f     = wid >> 1;
    const int hbase = (wid & 1) * 64;

    const float xm = x_min[c * F + f] * 128.f;
    const float xM = x_max[c * F + f] * 128.f;
    const float ym = y_min[c * F + f] * 128.f;
    const float yM = y_max[c * F + f] * 128.f;

    // column coefficients for cols lane, lane+64 (constant over h)
    int   j0[2], j1[2];
    float b0v[2], b1v[2], cb0[2], cb1[2];
    #pragma unroll
    for (int k = 0; k < 2; ++k) {
        const float wf = (float)(lane + 64 * k);
        const float v0 = fminf(fmaxf(wf + ym, 0.f), 128.f);
        const float v1 = fminf(fmaxf(wf + yM + 1.f, 0.f), 128.f);
        const float j0f = fminf(floorf(v0), 127.f);
        const float j1f = fminf(floorf(v1), 127.f);
        j0[k] = (int)j0f;  j1[k] = (int)j1f;
        b0v[k] = v0 - j0f; b1v[k] = v1 - j1f;
        cb0[k] = 1.f - b0v[k]; cb1[k] = 1.f - b1v[k];
    }

    const int rsub = lane >> 5;         // 0: row h, 1: row h+1
    const int wp   = (lane & 31) * 4;   // columns wp..wp+3
    float* Dw = Dbuf[wid];
    float* outf = out + ((size_t)bc * F + f) * (H * W);

    for (int it = 0; it < 32; ++it) {
        const int h = hbase + it * 2;

        // Stage A: row interpolation for rows h (lanes 0-31) and h+1 (lanes 32-63)
        const float hf = (float)(h + rsub);
        const float u0 = fminf(fmaxf(hf + xm, 0.f), 128.f);
        const float u1 = fminf(fmaxf(hf + xM + 1.f, 0.f), 128.f);
        const float i0f = fminf(floorf(u0), 127.f);
        const float i1f = fminf(floorf(u1), 127.f);
        const int   i0  = (int)i0f, i1 = (int)i1f;
        const float a0 = u0 - i0f, a1 = u1 - i1f;
        const float ca0 = 1.f - a0, ca1 = 1.f - a1;

        const float* p0 = I + i0 * STRIDE;
        const float* p1 = I + i1 * STRIDE;
        const float4 q0  = *(const float4*)(p0 + wp);
        const float4 q0b = *(const float4*)(p0 + STRIDE + wp);
        const float4 q1  = *(const float4*)(p1 + wp);
        const float4 q1b = *(const float4*)(p1 + STRIDE + wp);
        float4 d;
        d.x = ca1 * q1.x + a1 * q1b.x - ca0 * q0.x - a0 * q0b.x;
        d.y = ca1 * q1.y + a1 * q1b.y - ca0 * q0.y - a0 * q0b.y;
        d.z = ca1 * q1.z + a1 * q1b.z - ca0 * q0.z - a0 * q0b.z;
        d.w = ca1 * q1.w + a1 * q1b.w - ca0 * q0.w - a0 * q0b.w;
        *(float4*)(Dw + rsub * STRIDE + wp) = d;
        if ((lane & 31) == 31) {  // tail column 128 (lanes 31 and 63)
            Dw[rsub * STRIDE + 128] =
                ca1 * p1[128] + a1 * p1[STRIDE + 128]
              - ca0 * p0[128] - a0 * p0[STRIDE + 128];
        }
        // wave-synchronous RAW on Dw: same-wave DS ops are in order; compiler waits lgkmcnt

        // Stage B: column interpolation, 2 rows x 2 cols per lane (stride-1 gathers)
        #pragma unroll
        for (int rr = 0; rr < 2; ++rr) {
            const float* Dr = Dw + rr * STRIDE;
            #pragma unroll
            for (int k = 0; k < 2; ++k) {
                const float Dj0  = Dr[j0[k]];
                const float Dj0p = Dr[j0[k] + 1];
                const float Dj1  = Dr[j1[k]];
                const float Dj1p = Dr[j1[k] + 1];
                outf[(h + rr) * W + lane + 64 * k] =
                    cb1[k] * Dj1 + b1v[k] * Dj1p - cb0[k] * Dj0 - b0v[k] * Dj0p;
            }
        }
    }
}

extern "C" void kernel_launch(void* const* d_in, const int* in_sizes, int n_in,
                              void* d_out, int out_size, void* d_ws, size_t ws_size,
                              hipStream_t stream) {
    const float* in    = (const float*)d_in[0];
    const float* x_min = (const float*)d_in[1];
    const float* x_max = (const float*)d_in[2];
    const float* y_min = (const float*)d_in[3];
    const float* y_max = (const float*)d_in[4];
    float* outp = (float*)d_out;

    boxconv_kernel<<<dim3(8 * 32), dim3(1024), 0, stream>>>(
        in, x_min, x_max, y_min, y_max, outp);
}

// Round 7
// 155.340 us; speedup vs baseline: 1.0730x; 1.0137x over previous
//
#include <hip/hip_runtime.h>

// BoxConv2d via LDS integral image.
// Grid 512 = (b,c) x (half of F). Block 512 threads = 8 waves.
// Wave = (filter fi = wid>>1, h-half = wid&1); per iteration 2 output rows:
// lanes 0-31 -> row h, lanes 32-63 -> row h+1.
// LDS 78.6 KB -> 2 blocks/CU (desynchronized LDS-pipe demand).
// Main loop software-pipelined: next iteration's Stage-A reads issued between
// gather-issue and gather-use. Col-128 Drow tails precomputed per wave.

constexpr int H = 128, W = 128, C = 32, F = 8;
constexpr int STRIDE = 132;   // I row stride (floats); 16B-aligned rows
constexpr int NROW = 129;

__global__ __launch_bounds__(512, 4)
void boxconv_kernel(const float* __restrict__ in,
                    const float* __restrict__ x_min,
                    const float* __restrict__ x_max,
                    const float* __restrict__ y_min,
                    const float* __restrict__ y_max,
                    float* __restrict__ out)
{
    __shared__ float I[NROW * STRIDE];      // 68112 B
    __shared__ float Dbuf[8][2 * STRIDE];   //  8448 B
    __shared__ float Dtail[8][64];          //  2048 B  (total 78608 B)

    const int tid  = threadIdx.x;
    const int lane = tid & 63;
    const int wid  = tid >> 6;

    const int bc     = blockIdx.x >> 1;   // b*32 + c
    const int half_f = blockIdx.x & 1;    // filters 0-3 or 4-7
    const int c      = bc & 31;

    // ---- zero row 0 and col 0 of I (rest overwritten) ----
    if (tid < NROW) I[tid * STRIDE] = 0.f;
    else if (tid < NROW + STRIDE - 1) I[tid - 128] = 0.f;   // row0 cols 1..131
    __syncthreads();

    // ---- row scans: thread r scans input row r, writes I[r+1][1..128] ----
    const float* img = in + (size_t)bc * (H * W);
    if (tid < H) {
        const float4* row4 = (const float4*)(img + tid * W);
        float* Irow = I + (tid + 1) * STRIDE + 1;
        float acc = 0.f;
        #pragma unroll 8
        for (int w4 = 0; w4 < W / 4; ++w4) {
            float4 v = row4[w4];
            float s0 = acc + v.x, s1 = s0 + v.y, s2 = s1 + v.z, s3 = s2 + v.w;
            Irow[w4 * 4 + 0] = s0;
            Irow[w4 * 4 + 1] = s1;
            Irow[w4 * 4 + 2] = s2;
            Irow[w4 * 4 + 3] = s3;
            acc = s3;
        }
    }
    __syncthreads();

    // ---- col scans: thread t scans column t+1 over rows 1..128, reg-chunked ----
    if (tid < W) {
        const int cc = tid + 1;
        float acc = 0.f;
        for (int chunk = 0; chunk < 4; ++chunk) {
            const int r0 = 1 + chunk * 32;
            float v[32];
            #pragma unroll
            for (int i = 0; i < 32; ++i) v[i] = I[(r0 + i) * STRIDE + cc];
            #pragma unroll
            for (int i = 0; i < 32; ++i) { acc += v[i]; v[i] = acc; }
            #pragma unroll
            for (int i = 0; i < 32; ++i) I[(r0 + i) * STRIDE + cc] = v[i];
        }
    }
    __syncthreads();

    // ---- main loop setup: wave = (fi, h-half) ----
    const int fi    = wid >> 1;
    const int f     = half_f * 4 + fi;
    const int hbase = (wid & 1) * 64;

    const float xm = x_min[c * F + f] * 128.f;
    const float xM = x_max[c * F + f] * 128.f;
    const float ym = y_min[c * F + f] * 128.f;
    const float yM = y_max[c * F + f] * 128.f;

    // column coefficients for cols lane, lane+64 (constant over h)
    int   j0[2], j1[2];
    float b1v[2], cb1[2], nb0v[2], ncb0[2];
    #pragma unroll
    for (int k = 0; k < 2; ++k) {
        const float wf = (float)(lane + 64 * k);
        const float v0 = fminf(fmaxf(wf + ym, 0.f), 128.f);
        const float v1 = fminf(fmaxf(wf + yM + 1.f, 0.f), 128.f);
        const float j0f = fminf(floorf(v0), 127.f);
        const float j1f = fminf(floorf(v1), 127.f);
        j0[k] = (int)j0f;  j1[k] = (int)j1f;
        const float b0 = v0 - j0f, b1 = v1 - j1f;
        b1v[k] = b1; cb1[k] = 1.f - b1;
        nb0v[k] = -b0; ncb0[k] = -(1.f - b0);
    }

    const int rsub = lane >> 5;         // 0: row h, 1: row h+1
    const int wp   = (lane & 31) * 4;   // columns wp..wp+3
    float* Dw = Dbuf[wid];
    float* Dt = Dtail[wid];

    // row-interp coefficients + row addresses for row (h + rsub)
    auto rowCoef = [&](int h, const float*& p0, const float*& p1,
                       float& a0, float& a1, float& ca0, float& ca1) {
        const float hf = (float)(h + rsub);
        const float u0 = fminf(fmaxf(hf + xm, 0.f), 128.f);
        const float u1 = fminf(fmaxf(hf + xM + 1.f, 0.f), 128.f);
        const float i0f = fminf(floorf(u0), 127.f);
        const float i1f = fminf(floorf(u1), 127.f);
        a0 = u0 - i0f; a1 = u1 - i1f; ca0 = 1.f - a0; ca1 = 1.f - a1;
        p0 = I + (int)i0f * STRIDE;
        p1 = I + (int)i1f * STRIDE;
    };

    // ---- precompute col-128 Drow tails: lane r handles row hbase+r ----
    {
        const float hf = (float)(hbase + lane);
        const float u0 = fminf(fmaxf(hf + xm, 0.f), 128.f);
        const float u1 = fminf(fmaxf(hf + xM + 1.f, 0.f), 128.f);
        const float i0f = fminf(floorf(u0), 127.f);
        const float i1f = fminf(floorf(u1), 127.f);
        const int i0 = (int)i0f, i1 = (int)i1f;
        const float a0 = u0 - i0f, a1 = u1 - i1f;
        const float t = (1.f - a1) * I[i1 * STRIDE + 128] + a1 * I[(i1 + 1) * STRIDE + 128]
                      - (1.f - a0) * I[i0 * STRIDE + 128] - a0 * I[(i0 + 1) * STRIDE + 128];
        Dt[(lane & 1) * 32 + (lane >> 1)] = t;   // index [rsub*32 + it]
    }
    // same-wave DS ops are serviced in order -> no barrier needed (wave-private)

    float* outf = out + ((size_t)bc * F + f) * (size_t)(H * W);

    // ---- software-pipelined main loop ----
    const float *p0, *p1;
    float a0, a1, ca0, ca1;
    rowCoef(hbase, p0, p1, a0, a1, ca0, ca1);
    float4 q0  = *(const float4*)(p0 + wp);
    float4 q0b = *(const float4*)(p0 + STRIDE + wp);
    float4 q1  = *(const float4*)(p1 + wp);
    float4 q1b = *(const float4*)(p1 + STRIDE + wp);

    for (int it = 0; it < 32; ++it) {
        const int h = hbase + it * 2;

        // Stage A: row-interpolated difference -> Dw
        float4 d;
        d.x = ca1 * q1.x + a1 * q1b.x - ca0 * q0.x - a0 * q0b.x;
        d.y = ca1 * q1.y + a1 * q1b.y - ca0 * q0.y - a0 * q0b.y;
        d.z = ca1 * q1.z + a1 * q1b.z - ca0 * q0.z - a0 * q0b.z;
        d.w = ca1 * q1.w + a1 * q1b.w - ca0 * q0.w - a0 * q0b.w;
        *(float4*)(Dw + rsub * STRIDE + wp) = d;
        if ((lane & 31) == 31) Dw[rsub * STRIDE + 128] = Dt[rsub * 32 + it];

        // Stage B gathers: issue loads (in-order DS -> sees the writes above)
        float Dj0[2][2], Dj0p[2][2], Dj1[2][2], Dj1p[2][2];
        #pragma unroll
        for (int rr = 0; rr < 2; ++rr) {
            const float* Dr = Dw + rr * STRIDE;
            #pragma unroll
            for (int k = 0; k < 2; ++k) {
                const float* pj0 = Dr + j0[k];
                const float* pj1 = Dr + j1[k];
                Dj0[rr][k] = pj0[0]; Dj0p[rr][k] = pj0[1];
                Dj1[rr][k] = pj1[0]; Dj1p[rr][k] = pj1[1];
            }
        }

        // prefetch next iteration's Stage-A rows (independent of Dw)
        rowCoef(h + 2, p0, p1, a0, a1, ca0, ca1);
        q0  = *(const float4*)(p0 + wp);
        q0b = *(const float4*)(p0 + STRIDE + wp);
        q1  = *(const float4*)(p1 + wp);
        q1b = *(const float4*)(p1 + STRIDE + wp);

        // Stage B compute + store
        #pragma unroll
        for (int rr = 0; rr < 2; ++rr) {
            float* orow = outf + (size_t)(h + rr) * W;
            #pragma unroll
            for (int k = 0; k < 2; ++k) {
                const float o = cb1[k] * Dj1[rr][k] + b1v[k] * Dj1p[rr][k]
                              + ncb0[k] * Dj0[rr][k] + nb0v[k] * Dj0p[rr][k];
                orow[lane + 64 * k] = o;
            }
        }
    }
}

extern "C" void kernel_launch(void* const* d_in, const int* in_sizes, int n_in,
                              void* d_out, int out_size, void* d_ws, size_t ws_size,
                              hipStream_t stream) {
    const float* in    = (const float*)d_in[0];
    const float* x_min = (const float*)d_in[1];
    const float* x_max = (const float*)d_in[2];
    const float* y_min = (const float*)d_in[3];
    const float* y_max = (const float*)d_in[4];
    float* outp = (float*)d_out;

    boxconv_kernel<<<dim3(8 * 32 * 2), dim3(512), 0, stream>>>(
        in, x_min, x_max, y_min, y_max, outp);
}